// Round 1
// baseline (6492.380 us; speedup 1.0000x reference)
//
#include <hip/hip_runtime.h>
#include <hip/hip_bf16.h>

#define NN 4096
#define NQUINT 13
#define NCUBIC 5

using bf16 = __hip_bfloat16;
typedef __attribute__((ext_vector_type(4))) float f32x4;
typedef __attribute__((ext_vector_type(8))) short s16x8;

// ---------------------------------------------------------------------------
// async global->LDS, 16B per lane. LDS side MUST be wave-uniform base + lane*16.
// ---------------------------------------------------------------------------
__device__ inline void gl_lds16(const void* g, void* l) {
  __builtin_amdgcn_global_load_lds(
      (const __attribute__((address_space(1))) unsigned int*)(unsigned long long)(uintptr_t)g,
      (__attribute__((address_space(3))) unsigned int*)(uintptr_t)l,
      16, 0, 0);
}

// ---------------------------------------------------------------------------
// NT GEMM: C[i,j] = sum_k P[i,k] * Q[j,k]   (both row-major bf16, 4096^2)
// epilogue: out = alpha*aux[i,j] + beta*acc ; EPI==0 -> bf16 out, EPI==1 -> f32
// 128x128 block tile, BK=64, 4 waves (2x2 of 64x64), 16x16x32 bf16 MFMA.
// LDS chunk index XOR-swizzled by row&7 to kill ds_read_b128 bank conflicts;
// swizzle is applied on the GLOBAL address during staging (LDS side is forced
// lane-contiguous by global_load_lds semantics).
// ---------------------------------------------------------------------------
template <int EPI>
__global__ __launch_bounds__(256, 2) void gemm_nt(
    const bf16* __restrict__ P, const bf16* __restrict__ Q,
    void* __restrict__ Out, const bf16* __restrict__ aux,
    float alpha, float beta) {
  __shared__ bf16 lp[128 * 64];
  __shared__ bf16 lq[128 * 64];

  const int tid = threadIdx.x;
  const int lane = tid & 63;
  const int wv = tid >> 6;           // wave 0..3
  const int wr = wv >> 1, wc = wv & 1;
  const int bi = blockIdx.x, bj = blockIdx.y;

  const int m = lane & 15;           // row-in-16 for A/B frags, col for C
  const int qd = lane >> 4;          // 0..3 quad
  const int lrow = lane >> 3;        // staging: row-in-8 per instruction
  const int lchunk = lane & 7;       // staging: 16B chunk within 128B row

  f32x4 acc[4][4] = {};

  for (int k0 = 0; k0 < NN; k0 += 64) {
    __syncthreads();
#pragma unroll
    for (int s = 0; s < 4; ++s) {
      const int t = wv * 4 + s;                 // 0..15, covers rows t*8..t*8+7
      const int r = t * 8 + lrow;               // tile row 0..127
      const int gc = lchunk ^ (r & 7);          // global 16B-chunk (swizzle)
      const bf16* gp = P + (size_t)(bi * 128 + r) * NN + k0 + gc * 8;
      gl_lds16(gp, &lp[t * 512 + lane * 8]);
      const bf16* gq = Q + (size_t)(bj * 128 + r) * NN + k0 + gc * 8;
      gl_lds16(gq, &lq[t * 512 + lane * 8]);
    }
    __syncthreads();

#pragma unroll
    for (int sub = 0; sub < 2; ++sub) {
      s16x8 av[4], bv[4];
#pragma unroll
      for (int f = 0; f < 4; ++f) {
        const int ra = wr * 64 + f * 16 + m;
        const int ca = (sub * 4 + qd) ^ (ra & 7);
        av[f] = *(const s16x8*)&lp[ra * 64 + ca * 8];
        const int rb = wc * 64 + f * 16 + m;
        const int cb = (sub * 4 + qd) ^ (rb & 7);
        bv[f] = *(const s16x8*)&lq[rb * 64 + cb * 8];
      }
#pragma unroll
      for (int fr = 0; fr < 4; ++fr)
#pragma unroll
        for (int fc = 0; fc < 4; ++fc)
          acc[fr][fc] = __builtin_amdgcn_mfma_f32_16x16x32_bf16(
              av[fr], bv[fc], acc[fr][fc], 0, 0, 0);
    }
  }

  // Epilogue. C/D layout: col = lane&15, row = (lane>>4)*4 + reg  [m89/m91]
#pragma unroll
  for (int fr = 0; fr < 4; ++fr) {
#pragma unroll
    for (int fc = 0; fc < 4; ++fc) {
#pragma unroll
      for (int rg = 0; rg < 4; ++rg) {
        const int grow = bi * 128 + wr * 64 + fr * 16 + qd * 4 + rg;
        const int gcol = bj * 128 + wc * 64 + fc * 16 + m;
        const size_t idx = (size_t)grow * NN + gcol;
        float v = beta * acc[fr][fc][rg];
        if (alpha != 0.0f) v += alpha * (float)aux[idx];
        if (EPI == 0)
          ((bf16*)Out)[idx] = (bf16)v;
        else
          ((float*)Out)[idx] = v;
      }
    }
  }
}

// ---------------------------------------------------------------------------
// bf16 transpose, 64x64 LDS tiles (pad +1 to break bank conflicts)
// ---------------------------------------------------------------------------
__global__ void transpose_bf16(const bf16* __restrict__ in, bf16* __restrict__ out) {
  __shared__ bf16 tile[64][65];
  const int tx = threadIdx.x & 63;
  const int ty = threadIdx.x >> 6;  // 0..3
  const int bx = blockIdx.x, by = blockIdx.y;
#pragma unroll
  for (int rr = 0; rr < 16; ++rr) {
    const int row = rr * 4 + ty;
    tile[row][tx] = in[(size_t)(by * 64 + row) * NN + bx * 64 + tx];
  }
  __syncthreads();
#pragma unroll
  for (int rr = 0; rr < 16; ++rr) {
    const int row = rr * 4 + ty;
    out[(size_t)(bx * 64 + row) * NN + by * 64 + tx] = tile[tx][row];
  }
}

// ---------------------------------------------------------------------------
// Frobenius norm^2 reduction + scaled cast H -> bf16
// ---------------------------------------------------------------------------
__global__ void zero_f32(float* p) { *p = 0.0f; }

__global__ void reduce_sumsq(const float* __restrict__ h, float* __restrict__ sum) {
  float acc = 0.0f;
  const size_t total = (size_t)NN * NN;
  for (size_t i = (size_t)blockIdx.x * blockDim.x + threadIdx.x; i < total;
       i += (size_t)gridDim.x * blockDim.x) {
    const float v = h[i];
    acc += v * v;
  }
  for (int off = 32; off; off >>= 1) acc += __shfl_down(acc, off, 64);
  __shared__ float ws[4];
  const int lane = threadIdx.x & 63, wv = threadIdx.x >> 6;
  if (lane == 0) ws[wv] = acc;
  __syncthreads();
  if (threadIdx.x == 0) atomicAdd(sum, ws[0] + ws[1] + ws[2] + ws[3]);
}

__global__ void scale_cast(const float* __restrict__ h, const float* __restrict__ sum,
                           bf16* __restrict__ xb) {
  const float inv = rsqrtf(*sum);
  const size_t i = ((size_t)blockIdx.x * blockDim.x + threadIdx.x) * 4;
  const float4 v = *(const float4*)(h + i);
  union { bf16 b[4]; ushort4 u; } cvt;
  cvt.b[0] = (bf16)(v.x * inv);
  cvt.b[1] = (bf16)(v.y * inv);
  cvt.b[2] = (bf16)(v.z * inv);
  cvt.b[3] = (bf16)(v.w * inv);
  *(ushort4*)(xb + i) = cvt.u;
}

// ---------------------------------------------------------------------------
// Launch: polar factor via scaled quintic (Muon) + cubic Newton-Schulz.
//   ws layout: P0 [0,32M) | P1 [32M,64M) | Ab [64M,96M) | sum @96M  (96MB+4B)
//   Bb lives in upper half of d_out (freed before the final fp32 write).
// ---------------------------------------------------------------------------
extern "C" void kernel_launch(void* const* d_in, const int* in_sizes, int n_in,
                              void* d_out, int out_size, void* d_ws, size_t ws_size,
                              hipStream_t stream) {
  (void)in_sizes; (void)n_in; (void)out_size; (void)ws_size;
  const float* H = (const float*)d_in[0];
  float* out = (float*)d_out;
  char* ws = (char*)d_ws;

  bf16* P0 = (bf16*)ws;
  bf16* P1 = (bf16*)(ws + ((size_t)32 << 20));
  bf16* Ab = (bf16*)(ws + ((size_t)64 << 20));
  float* sum = (float*)(ws + ((size_t)96 << 20));
  bf16* Bb = (bf16*)((char*)d_out + ((size_t)32 << 20));

  zero_f32<<<1, 1, 0, stream>>>(sum);
  reduce_sumsq<<<1024, 256, 0, stream>>>(H, sum);
  scale_cast<<<(NN * (size_t)NN) / 4 / 256, 256, 0, stream>>>(H, sum, P0);

  bf16* X = P0;
  bf16* Y = P1;  // holds X^T, then X' (X^T is dead once A is computed)
  const dim3 g(32, 32), tb(256), gt(64, 64);
  const float qa = 3.4445f, qb = -4.7750f, qc = 2.0315f;

  for (int it = 0; it < NQUINT + NCUBIC; ++it) {
    const bool quint = it < NQUINT;
    const bool last = (it == NQUINT + NCUBIC - 1);
    transpose_bf16<<<gt, tb, 0, stream>>>(X, Y);                       // Y = X^T
    gemm_nt<0><<<g, tb, 0, stream>>>(Y, Y, Ab, (bf16*)nullptr, 0.0f, 1.0f); // A = X^T X
    if (quint) {
      gemm_nt<0><<<g, tb, 0, stream>>>(Ab, Ab, Bb, Ab, qb, qc);        // B = qb*A + qc*A^2
      gemm_nt<0><<<g, tb, 0, stream>>>(X, Bb, Y, X, qa, 1.0f);         // X' = qa*X + X*B
      bf16* t = X; X = Y; Y = t;
    } else if (!last) {
      gemm_nt<0><<<g, tb, 0, stream>>>(X, Ab, Y, X, 1.5f, -0.5f);      // X' = 1.5X - 0.5 X*A
      bf16* t = X; X = Y; Y = t;
    } else {
      gemm_nt<1><<<g, tb, 0, stream>>>(X, Ab, out, X, 1.5f, -0.5f);    // final, fp32 out
    }
  }
}

// Round 2
// 5321.099 us; speedup vs baseline: 1.2201x; 1.2201x over previous
//
#include <hip/hip_runtime.h>
#include <hip/hip_bf16.h>

#define NN 4096
#define NITER 12   // 9 Muon growth + 3 polish quintics
#define NGROW 9
#define NPOW 12    // power-iteration matvecs for sigma_max estimate

using bf16 = __hip_bfloat16;
typedef __attribute__((ext_vector_type(4))) float f32x4;
typedef __attribute__((ext_vector_type(8))) short s16x8;
typedef __attribute__((ext_vector_type(8))) unsigned short u16x8;

__device__ inline float bf2f(unsigned short u) {
  union { unsigned int i; float f; } c; c.i = ((unsigned int)u) << 16; return c.f;
}
__device__ inline unsigned short f2bf(float f) {
  bf16 t = (bf16)f; return *(unsigned short*)&t;
}

// ---------------------------------------------------------------------------
// async global->LDS, 16B per lane. LDS side MUST be wave-uniform base + lane*16.
// ---------------------------------------------------------------------------
__device__ inline void gl_lds16(const void* g, void* l) {
  __builtin_amdgcn_global_load_lds(
      (const __attribute__((address_space(1))) unsigned int*)(unsigned long long)(uintptr_t)g,
      (__attribute__((address_space(3))) unsigned int*)(uintptr_t)l,
      16, 0, 0);
}

// ---------------------------------------------------------------------------
// NT GEMM: C[i,j] = sum_k P[i,k] * Q[j,k]  (row-major bf16, 4096^2)
// epilogue: out = alpha*aux + beta*acc ; EPI==0 -> bf16 out, EPI==1 -> f32
// TRI==1: compute only lower-triangle blocks (bj<=bi); mirror kernel fills rest.
// ---------------------------------------------------------------------------
template <int EPI, int TRI>
__global__ __launch_bounds__(256, 2) void gemm_nt(
    const bf16* __restrict__ P, const bf16* __restrict__ Q,
    void* __restrict__ Out, const bf16* __restrict__ aux,
    float alpha, float beta) {
  if (TRI && blockIdx.y > blockIdx.x) return;
  __shared__ bf16 lp[128 * 64];
  __shared__ bf16 lq[128 * 64];

  const int tid = threadIdx.x;
  const int lane = tid & 63;
  const int wv = tid >> 6;
  const int wr = wv >> 1, wc = wv & 1;
  const int bi = blockIdx.x, bj = blockIdx.y;

  const int m = lane & 15;
  const int qd = lane >> 4;
  const int lrow = lane >> 3;
  const int lchunk = lane & 7;

  f32x4 acc[4][4] = {};

  for (int k0 = 0; k0 < NN; k0 += 64) {
    __syncthreads();
#pragma unroll
    for (int s = 0; s < 4; ++s) {
      const int t = wv * 4 + s;
      const int r = t * 8 + lrow;
      const int gc = lchunk ^ (r & 7);
      const bf16* gp = P + (size_t)(bi * 128 + r) * NN + k0 + gc * 8;
      gl_lds16(gp, &lp[t * 512 + lane * 8]);
      const bf16* gq = Q + (size_t)(bj * 128 + r) * NN + k0 + gc * 8;
      gl_lds16(gq, &lq[t * 512 + lane * 8]);
    }
    __syncthreads();

#pragma unroll
    for (int sub = 0; sub < 2; ++sub) {
      s16x8 av[4], bv[4];
#pragma unroll
      for (int f = 0; f < 4; ++f) {
        const int ra = wr * 64 + f * 16 + m;
        const int ca = (sub * 4 + qd) ^ (ra & 7);
        av[f] = *(const s16x8*)&lp[ra * 64 + ca * 8];
        const int rb = wc * 64 + f * 16 + m;
        const int cb = (sub * 4 + qd) ^ (rb & 7);
        bv[f] = *(const s16x8*)&lq[rb * 64 + cb * 8];
      }
#pragma unroll
      for (int fr = 0; fr < 4; ++fr)
#pragma unroll
        for (int fc = 0; fc < 4; ++fc)
          acc[fr][fc] = __builtin_amdgcn_mfma_f32_16x16x32_bf16(
              av[fr], bv[fc], acc[fr][fc], 0, 0, 0);
    }
  }

  // C/D layout: col = lane&15, row = (lane>>4)*4 + reg  [m89/m91]
#pragma unroll
  for (int fr = 0; fr < 4; ++fr) {
#pragma unroll
    for (int fc = 0; fc < 4; ++fc) {
#pragma unroll
      for (int rg = 0; rg < 4; ++rg) {
        const int grow = bi * 128 + wr * 64 + fr * 16 + qd * 4 + rg;
        const int gcol = bj * 128 + wc * 64 + fc * 16 + m;
        const size_t idx = (size_t)grow * NN + gcol;
        float v = beta * acc[fr][fc][rg];
        if (alpha != 0.0f) v += alpha * (float)aux[idx];
        if (EPI == 0)
          ((bf16*)Out)[idx] = (bf16)v;
        else
          ((float*)Out)[idx] = v;
      }
    }
  }
}

// ---------------------------------------------------------------------------
// bf16 transpose, 64x64 LDS tiles (pad +1 to break bank conflicts)
// ---------------------------------------------------------------------------
__global__ void transpose_bf16(const bf16* __restrict__ in, bf16* __restrict__ out) {
  __shared__ bf16 tile[64][65];
  const int tx = threadIdx.x & 63;
  const int ty = threadIdx.x >> 6;
  const int bx = blockIdx.x, by = blockIdx.y;
#pragma unroll
  for (int rr = 0; rr < 16; ++rr) {
    const int row = rr * 4 + ty;
    tile[row][tx] = in[(size_t)(by * 64 + row) * NN + bx * 64 + tx];
  }
  __syncthreads();
#pragma unroll
  for (int rr = 0; rr < 16; ++rr) {
    const int row = rr * 4 + ty;
    out[(size_t)(bx * 64 + row) * NN + by * 64 + tx] = tile[tx][row];
  }
}

// ---------------------------------------------------------------------------
// Mirror lower triangle -> upper triangle in place (A[i,j]=A[j,i], j>i).
// Dest 64-tile (bx,by) with by>bx; src tile (by,bx) is strictly-lower and is
// never written by any mirror block -> in-place race-free.
// ---------------------------------------------------------------------------
__global__ void mirror_upper(bf16* __restrict__ A) {
  const int bx = blockIdx.x, by = blockIdx.y;
  if (by <= bx) return;
  __shared__ bf16 tile[64][65];
  const int tx = threadIdx.x & 63;
  const int ty = threadIdx.x >> 6;
#pragma unroll
  for (int rr = 0; rr < 16; ++rr) {
    const int row = rr * 4 + ty;
    tile[row][tx] = A[(size_t)(by * 64 + row) * NN + bx * 64 + tx];
  }
  __syncthreads();
#pragma unroll
  for (int rr = 0; rr < 16; ++rr) {
    const int row = rr * 4 + ty;
    A[(size_t)(bx * 64 + row) * NN + by * 64 + tx] = tile[tx][row];
  }
}

// ---------------------------------------------------------------------------
// Power iteration matvec on symmetric bf16 A: vout = A*(vin*rsqrt(*snin)),
// atomicAdd ||vout||^2 into *snout. One wave per row.
// ---------------------------------------------------------------------------
__global__ __launch_bounds__(256) void powmv(const bf16* __restrict__ A,
                                             const float* __restrict__ vin,
                                             const float* __restrict__ snin,
                                             float* __restrict__ vout,
                                             float* __restrict__ snout) {
  const float scale = rsqrtf(*snin);
  const int row = blockIdx.x * 4 + (threadIdx.x >> 6);
  const int lane = threadIdx.x & 63;
  const unsigned short* arow = (const unsigned short*)A + (size_t)row * NN;
  float acc = 0.0f;
#pragma unroll
  for (int p = 0; p < 8; ++p) {
    const int c = p * 512 + lane * 8;
    const u16x8 av = *(const u16x8*)(arow + c);
    const float4 w0 = *(const float4*)(vin + c);
    const float4 w1 = *(const float4*)(vin + c + 4);
    acc += bf2f(av[0]) * w0.x + bf2f(av[1]) * w0.y + bf2f(av[2]) * w0.z +
           bf2f(av[3]) * w0.w + bf2f(av[4]) * w1.x + bf2f(av[5]) * w1.y +
           bf2f(av[6]) * w1.z + bf2f(av[7]) * w1.w;
  }
  for (int off = 32; off; off >>= 1) acc += __shfl_down(acc, off, 64);
  if (lane == 0) {
    const float u = acc * scale;
    vout[row] = u;
    atomicAdd(snout, u * u);
  }
}

// ---------------------------------------------------------------------------
// init: zero scalar slots (slot1=1 for ||v0||^2), write v0 = +-1/64
// ---------------------------------------------------------------------------
__global__ void init_pw(float* __restrict__ v0, float* __restrict__ slots) {
  const int t = threadIdx.x;
  if (t < 64) slots[t] = (t == 1) ? 1.0f : 0.0f;
  for (int i = t; i < NN; i += 256) {
    const unsigned h = (unsigned)i * 2654435761u;
    v0[i] = ((h >> 16) & 1) ? 0.015625f : -0.015625f;
  }
}

// ---------------------------------------------------------------------------
// ||H||_F^2 -> slots[0]
// ---------------------------------------------------------------------------
__global__ void reduce_sumsq(const float* __restrict__ h, float* __restrict__ slots) {
  float acc = 0.0f;
  const size_t total = (size_t)NN * NN;
  for (size_t i = (size_t)blockIdx.x * blockDim.x + threadIdx.x; i < total;
       i += (size_t)gridDim.x * blockDim.x) {
    const float v = h[i];
    acc += v * v;
  }
  for (int off = 32; off; off >>= 1) acc += __shfl_down(acc, off, 64);
  __shared__ float ws[4];
  const int lane = threadIdx.x & 63, wv = threadIdx.x >> 6;
  if (lane == 0) ws[wv] = acc;
  __syncthreads();
  if (threadIdx.x == 0) atomicAdd(&slots[0], ws[0] + ws[1] + ws[2] + ws[3]);
}

// ---------------------------------------------------------------------------
// H (fp32) -> bf16, scaled. mode 0: /||H||_F. mode 1: /(||H||_F*sqrt(1.10*lam))
// where lam = sqrt(slots[1+NPOW]) estimates lambda_max(A') = (smax/||H||_F)^2.
// ---------------------------------------------------------------------------
__global__ void scale_cast(const float* __restrict__ h, const float* __restrict__ slots,
                           bf16* __restrict__ xb, int mode) {
  float inv = rsqrtf(slots[0]);
  if (mode) inv *= rsqrtf(1.10f * sqrtf(slots[1 + NPOW]));
  const size_t i = ((size_t)blockIdx.x * blockDim.x + threadIdx.x) * 4;
  const float4 v = *(const float4*)(h + i);
  union { bf16 b[4]; ushort4 u; } cvt;
  cvt.b[0] = (bf16)(v.x * inv);
  cvt.b[1] = (bf16)(v.y * inv);
  cvt.b[2] = (bf16)(v.z * inv);
  cvt.b[3] = (bf16)(v.w * inv);
  *(ushort4*)(xb + i) = cvt.u;
}

// ---------------------------------------------------------------------------
// A *= 1/(1.10*lam)  so that A0 = X0^T X0 for the rescaled X0.
// ---------------------------------------------------------------------------
__global__ void rescale_bf16(bf16* __restrict__ a, const float* __restrict__ slots) {
  const float cA = 1.0f / (1.10f * sqrtf(slots[1 + NPOW]));
  const size_t i = ((size_t)blockIdx.x * 256 + threadIdx.x) * 8;
  unsigned short* p = (unsigned short*)a + i;
  u16x8 v = *(u16x8*)p;
  u16x8 o;
#pragma unroll
  for (int j = 0; j < 8; ++j) o[j] = f2bf(bf2f(v[j]) * cA);
  *(u16x8*)p = o;
}

// ---------------------------------------------------------------------------
// Polar factor via sigma_max-normalized quintic Newton-Schulz.
//   X0 = H/sigma_hat; 9x Muon quintic (growth) + 3x (15/8,-5/4,3/8) (polish).
//   Per iter: Y=X^T; A=tri(Y Y^T)+mirror; B=tri(qb A+qc A^2)+mirror; X'=qa X+X B.
//   ws: P0 [0,32M) | P1 [32M,64M) | Ab [64M,96M)
//   d_out: v0/v1/slots in first 48KB (preamble only), Bb at +32MB (dead before
//   the final fp32 write, whose B lives in the dead ws X^T buffer -> no race).
// ---------------------------------------------------------------------------
extern "C" void kernel_launch(void* const* d_in, const int* in_sizes, int n_in,
                              void* d_out, int out_size, void* d_ws, size_t ws_size,
                              hipStream_t stream) {
  (void)in_sizes; (void)n_in; (void)out_size; (void)ws_size;
  const float* H = (const float*)d_in[0];
  float* out = (float*)d_out;
  char* ws = (char*)d_ws;

  bf16* P0 = (bf16*)ws;
  bf16* P1 = (bf16*)(ws + ((size_t)32 << 20));
  bf16* Ab = (bf16*)(ws + ((size_t)64 << 20));
  bf16* Bb = (bf16*)((char*)d_out + ((size_t)32 << 20));
  float* v0 = (float*)d_out;
  float* v1 = (float*)((char*)d_out + 16384);
  float* slots = (float*)((char*)d_out + 32768);

  const dim3 g(32, 32), tb(256), gt(64, 64);

  // --- preamble: Frobenius scale, A' = X0'^T X0', power-iterate lambda_max ---
  init_pw<<<1, 256, 0, stream>>>(v0, slots);
  reduce_sumsq<<<1024, 256, 0, stream>>>(H, slots);
  scale_cast<<<(NN * (size_t)NN) / 4 / 256, 256, 0, stream>>>(H, slots, P0, 0);
  transpose_bf16<<<gt, tb, 0, stream>>>(P0, P1);
  gemm_nt<0, 1><<<g, tb, 0, stream>>>(P1, P1, Ab, (bf16*)nullptr, 0.0f, 1.0f);
  mirror_upper<<<gt, tb, 0, stream>>>(Ab);
  for (int k = 0; k < NPOW; ++k) {
    const float* vi = (k & 1) ? v1 : v0;
    float* vo = (k & 1) ? v0 : v1;
    powmv<<<1024, 256, 0, stream>>>(Ab, vi, &slots[1 + k], vo, &slots[2 + k]);
  }
  rescale_bf16<<<(NN * (size_t)NN) / 8 / 256, 256, 0, stream>>>(Ab, slots);
  scale_cast<<<(NN * (size_t)NN) / 4 / 256, 256, 0, stream>>>(H, slots, P0, 1);

  // --- quintic iterations ---
  bf16* X = P0;
  bf16* Y = P1;
  const float GA = 3.4445f, GB = -4.7750f, GC = 2.0315f;   // Muon growth
  const float PA = 1.875f, PB = -1.25f, PC = 0.375f;        // tangent polish

  for (int it = 0; it < NITER; ++it) {
    const bool polish = it >= NGROW;
    const bool last = (it == NITER - 1);
    const float qa = polish ? PA : GA, qb = polish ? PB : GB, qc = polish ? PC : GC;

    if (it > 0) {  // iteration 0 reuses the preamble's (rescaled) A
      transpose_bf16<<<gt, tb, 0, stream>>>(X, Y);
      gemm_nt<0, 1><<<g, tb, 0, stream>>>(Y, Y, Ab, (bf16*)nullptr, 0.0f, 1.0f);
      mirror_upper<<<gt, tb, 0, stream>>>(Ab);
    }
    bf16* Bdst = last ? Y : Bb;  // final B must not alias d_out (race w/ C-write)
    gemm_nt<0, 1><<<g, tb, 0, stream>>>(Ab, Ab, Bdst, Ab, qb, qc);
    mirror_upper<<<gt, tb, 0, stream>>>(Bdst);
    if (!last) {
      gemm_nt<0, 0><<<g, tb, 0, stream>>>(X, Bdst, Y, X, qa, 1.0f);
      bf16* t = X; X = Y; Y = t;
    } else {
      gemm_nt<1, 0><<<g, tb, 0, stream>>>(X, Bdst, out, X, qa, 1.0f);
    }
  }
}

// Round 3
// 4585.655 us; speedup vs baseline: 1.4158x; 1.1604x over previous
//
#include <hip/hip_runtime.h>
#include <hip/hip_bf16.h>
#include <hip/hip_fp16.h>

#define NN 4096
#define NGROW 8
#define NPOL 2
#define NITER (NGROW + NPOL)
#define NPOW 12
#define NTRI 528          // 32*33/2 lower-triangle 128-tiles
#define PRESCALE 32.0f    // keeps pre-rescale A entries in f16 normal range

using f16 = _Float16;
typedef __attribute__((ext_vector_type(4))) float f32x4;
typedef __attribute__((ext_vector_type(8))) f16 h16x8;

// ---------------------------------------------------------------------------
// async global->LDS, 16B per lane. LDS side MUST be wave-uniform base + lane*16.
// ---------------------------------------------------------------------------
__device__ inline void gl_lds16(const void* g, void* l) {
  __builtin_amdgcn_global_load_lds(
      (const __attribute__((address_space(1))) unsigned int*)(unsigned long long)(uintptr_t)g,
      (__attribute__((address_space(3))) unsigned int*)(uintptr_t)l,
      16, 0, 0);
}

// ---------------------------------------------------------------------------
// NT GEMM: C[i,j] = sum_k P[i,k] * Q[j,k]  (row-major f16, 4096^2)
// epilogue: out = alpha*aux + beta*acc ; EPI==0 -> f16 out, EPI==1 -> f32
// TRI==1: 1-D grid of 528 lower-triangle blocks; epilogue also writes the
// mirrored (bj,bi) tile (valid because every TRI product is symmetric).
// launch_bounds(256,4): 64 VGPR + 64 AGPR = 128 regs -> 4 blocks/CU, so all
// 528 tri blocks are co-resident in one scheduling round (fixes R2's tail).
// ---------------------------------------------------------------------------
template <int EPI, int TRI>
__global__ __launch_bounds__(256, 4) void gemm_nt(
    const f16* __restrict__ P, const f16* __restrict__ Q,
    void* __restrict__ Out, const f16* __restrict__ aux,
    float alpha, float beta) {
  int bi, bj;
  if (TRI) {
    const int t = blockIdx.x;
    int r = (int)((sqrtf(8.0f * (float)t + 1.0f) - 1.0f) * 0.5f);
    while ((r + 1) * (r + 2) / 2 <= t) ++r;
    while (r * (r + 1) / 2 > t) --r;
    bi = r;
    bj = t - r * (r + 1) / 2;
  } else {
    bi = blockIdx.x;
    bj = blockIdx.y;
  }

  __shared__ f16 lp[128 * 64];
  __shared__ f16 lq[128 * 64];

  const int tid = threadIdx.x;
  const int lane = tid & 63;
  const int wv = tid >> 6;
  const int wr = wv >> 1, wc = wv & 1;

  const int m = lane & 15;
  const int qd = lane >> 4;
  const int lrow = lane >> 3;
  const int lchunk = lane & 7;

  f32x4 acc[4][4] = {};

  for (int k0 = 0; k0 < NN; k0 += 64) {
    __syncthreads();
#pragma unroll
    for (int s = 0; s < 4; ++s) {
      const int t = wv * 4 + s;
      const int r = t * 8 + lrow;
      const int gc = lchunk ^ (r & 7);          // XOR swizzle (0 bank conflicts, R1)
      const f16* gp = P + (size_t)(bi * 128 + r) * NN + k0 + gc * 8;
      gl_lds16(gp, &lp[t * 512 + lane * 8]);
      const f16* gq = Q + (size_t)(bj * 128 + r) * NN + k0 + gc * 8;
      gl_lds16(gq, &lq[t * 512 + lane * 8]);
    }
    __syncthreads();

#pragma unroll
    for (int sub = 0; sub < 2; ++sub) {
      h16x8 av[4], bv[4];
#pragma unroll
      for (int f = 0; f < 4; ++f) {
        const int ra = wr * 64 + f * 16 + m;
        const int ca = (sub * 4 + qd) ^ (ra & 7);
        av[f] = *(const h16x8*)&lp[ra * 64 + ca * 8];
        const int rb = wc * 64 + f * 16 + m;
        const int cb = (sub * 4 + qd) ^ (rb & 7);
        bv[f] = *(const h16x8*)&lq[rb * 64 + cb * 8];
      }
#pragma unroll
      for (int fr = 0; fr < 4; ++fr)
#pragma unroll
        for (int fc = 0; fc < 4; ++fc)
          acc[fr][fc] = __builtin_amdgcn_mfma_f32_16x16x32_f16(
              av[fr], bv[fc], acc[fr][fc], 0, 0, 0);
    }
  }

  // C/D layout: col = lane&15, row = (lane>>4)*4 + reg  [m89/m91, dtype-indep]
#pragma unroll
  for (int fr = 0; fr < 4; ++fr) {
#pragma unroll
    for (int fc = 0; fc < 4; ++fc) {
#pragma unroll
      for (int rg = 0; rg < 4; ++rg) {
        const int lr = wr * 64 + fr * 16 + qd * 4 + rg;   // row within tile
        const int lc = wc * 64 + fc * 16 + m;             // col within tile
        const size_t idx = (size_t)(bi * 128 + lr) * NN + bj * 128 + lc;
        float v = beta * acc[fr][fc][rg];
        if (alpha != 0.0f) v += alpha * (float)aux[idx];
        if (EPI == 0)
          ((f16*)Out)[idx] = (f16)v;
        else
          ((float*)Out)[idx] = v;
        if (TRI && bi != bj) {  // fused mirror: symmetric product
          const size_t idxT = (size_t)(bj * 128 + lc) * NN + bi * 128 + lr;
          ((f16*)Out)[idxT] = (f16)v;
        }
      }
    }
  }
}

// ---------------------------------------------------------------------------
// 2-byte transpose, 64x64 LDS tiles (pad +1 to break bank conflicts)
// ---------------------------------------------------------------------------
__global__ void transpose_h(const unsigned short* __restrict__ in,
                            unsigned short* __restrict__ out) {
  __shared__ unsigned short tile[64][65];
  const int tx = threadIdx.x & 63;
  const int ty = threadIdx.x >> 6;
  const int bx = blockIdx.x, by = blockIdx.y;
#pragma unroll
  for (int rr = 0; rr < 16; ++rr) {
    const int row = rr * 4 + ty;
    tile[row][tx] = in[(size_t)(by * 64 + row) * NN + bx * 64 + tx];
  }
  __syncthreads();
#pragma unroll
  for (int rr = 0; rr < 16; ++rr) {
    const int row = rr * 4 + ty;
    out[(size_t)(bx * 64 + row) * NN + by * 64 + tx] = tile[tx][row];
  }
}

// ---------------------------------------------------------------------------
// Power iteration matvec on symmetric f16 A: vout = A*(vin*rsqrt(*snin)),
// atomicAdd ||vout||^2 into *snout. One wave per row.
// ---------------------------------------------------------------------------
__global__ __launch_bounds__(256) void powmv(const f16* __restrict__ A,
                                             const float* __restrict__ vin,
                                             const float* __restrict__ snin,
                                             float* __restrict__ vout,
                                             float* __restrict__ snout) {
  const float scale = rsqrtf(*snin);
  const int row = blockIdx.x * 4 + (threadIdx.x >> 6);
  const int lane = threadIdx.x & 63;
  const f16* arow = A + (size_t)row * NN;
  float acc = 0.0f;
#pragma unroll
  for (int p = 0; p < 8; ++p) {
    const int c = p * 512 + lane * 8;
    const h16x8 av = *(const h16x8*)(arow + c);
    const float4 w0 = *(const float4*)(vin + c);
    const float4 w1 = *(const float4*)(vin + c + 4);
    acc += (float)av[0] * w0.x + (float)av[1] * w0.y + (float)av[2] * w0.z +
           (float)av[3] * w0.w + (float)av[4] * w1.x + (float)av[5] * w1.y +
           (float)av[6] * w1.z + (float)av[7] * w1.w;
  }
  for (int off = 32; off; off >>= 1) acc += __shfl_down(acc, off, 64);
  if (lane == 0) {
    const float u = acc * scale;
    vout[row] = u;
    atomicAdd(snout, u * u);
  }
}

// ---------------------------------------------------------------------------
// init: slots[64] (slot1=1 for ||v0||^2), v0 = +-1/64
// ---------------------------------------------------------------------------
__global__ void init_pw(float* __restrict__ v0, float* __restrict__ slots) {
  const int t = threadIdx.x;
  if (t < 64) slots[t] = (t == 1) ? 1.0f : 0.0f;
  for (int i = t; i < NN; i += 256) {
    const unsigned h = (unsigned)i * 2654435761u;
    v0[i] = ((h >> 16) & 1) ? 0.015625f : -0.015625f;
  }
}

// ---------------------------------------------------------------------------
// ||H||_F^2 -> slots[0]
// ---------------------------------------------------------------------------
__global__ void reduce_sumsq(const float* __restrict__ h, float* __restrict__ slots) {
  float acc = 0.0f;
  const size_t total = (size_t)NN * NN;
  for (size_t i = (size_t)blockIdx.x * blockDim.x + threadIdx.x; i < total;
       i += (size_t)gridDim.x * blockDim.x) {
    const float v = h[i];
    acc += v * v;
  }
  for (int off = 32; off; off >>= 1) acc += __shfl_down(acc, off, 64);
  __shared__ float ws[4];
  const int lane = threadIdx.x & 63, wv = threadIdx.x >> 6;
  if (lane == 0) ws[wv] = acc;
  __syncthreads();
  if (threadIdx.x == 0) atomicAdd(&slots[0], ws[0] + ws[1] + ws[2] + ws[3]);
}

// ---------------------------------------------------------------------------
// H (fp32) -> f16, scaled.
//   mode 0: X0' = H * PRESCALE / ||H||_F          (pre-scale for lambda est)
//   mode 1: X0  = H * PRESCALE / (||H||_F * sqrt(1.10*lam_hat))
//   lam_hat = sqrt(slots[1+NPOW]) = power-iter estimate of lambda_max(A')
//   (PRESCALE cancels: X0 = H/(||H||_F*sqrt(1.10*lam_true)), lam_true=lam_hat/1024)
// ---------------------------------------------------------------------------
__global__ void scale_cast(const float* __restrict__ h, const float* __restrict__ slots,
                           f16* __restrict__ xb, int mode) {
  float inv = rsqrtf(slots[0]) * PRESCALE;
  if (mode) inv *= rsqrtf(1.10f * sqrtf(slots[1 + NPOW]));
  const size_t i = ((size_t)blockIdx.x * blockDim.x + threadIdx.x) * 4;
  const float4 v = *(const float4*)(h + i);
  union { f16 hh[4]; ushort4 u; } cvt;
  cvt.hh[0] = (f16)(v.x * inv);
  cvt.hh[1] = (f16)(v.y * inv);
  cvt.hh[2] = (f16)(v.z * inv);
  cvt.hh[3] = (f16)(v.w * inv);
  *(ushort4*)(xb + i) = cvt.u;
}

// ---------------------------------------------------------------------------
// A *= 1/(1.10*lam_hat)  so A0 = X0^T X0 for the mode-1-scaled X0.
// ---------------------------------------------------------------------------
__global__ void rescale_f16(f16* __restrict__ a, const float* __restrict__ slots) {
  const float cA = 1.0f / (1.10f * sqrtf(slots[1 + NPOW]));
  const size_t i = ((size_t)blockIdx.x * 256 + threadIdx.x) * 8;
  h16x8 v = *(h16x8*)(a + i);
  h16x8 o;
#pragma unroll
  for (int j = 0; j < 8; ++j) o[j] = (f16)((float)v[j] * cA);
  *(h16x8*)(a + i) = o;
}

// ---------------------------------------------------------------------------
// Polar factor via sigma_max-normalized quintic Newton-Schulz, fp16 GEMMs.
//   8x Muon growth + 2x tangent polish (15/8,-5/4,3/8).
//   Per iter: Y=X^T; A=tri(Y Y^T)+fused mirror; B=tri(qb A+qc A^2)+mirror;
//   X'=qa X+X B (full).
//   ws: P0 [0,32M) | P1 [32M,64M) | Ab [64M,96M)
//   d_out: v0/v1/slots in first 48KB (preamble only), Bb at +32MB; final B
//   goes to the dead ws X^T buffer so the fp32 C-write never races it.
// ---------------------------------------------------------------------------
extern "C" void kernel_launch(void* const* d_in, const int* in_sizes, int n_in,
                              void* d_out, int out_size, void* d_ws, size_t ws_size,
                              hipStream_t stream) {
  (void)in_sizes; (void)n_in; (void)out_size; (void)ws_size;
  const float* H = (const float*)d_in[0];
  float* out = (float*)d_out;
  char* ws = (char*)d_ws;

  f16* P0 = (f16*)ws;
  f16* P1 = (f16*)(ws + ((size_t)32 << 20));
  f16* Ab = (f16*)(ws + ((size_t)64 << 20));
  f16* Bb = (f16*)((char*)d_out + ((size_t)32 << 20));
  float* v0 = (float*)d_out;
  float* v1 = (float*)((char*)d_out + 16384);
  float* slots = (float*)((char*)d_out + 32768);

  const dim3 gfull(32, 32), tb(256), gt(64, 64);

  // --- preamble: Frobenius scale, A' = X0'^T X0', power-iterate lambda_max ---
  init_pw<<<1, 256, 0, stream>>>(v0, slots);
  reduce_sumsq<<<1024, 256, 0, stream>>>(H, slots);
  scale_cast<<<(NN * (size_t)NN) / 4 / 256, 256, 0, stream>>>(H, slots, P0, 0);
  transpose_h<<<gt, tb, 0, stream>>>((const unsigned short*)P0, (unsigned short*)P1);
  gemm_nt<0, 1><<<NTRI, tb, 0, stream>>>(P1, P1, Ab, (f16*)nullptr, 0.0f, 1.0f);
  for (int k = 0; k < NPOW; ++k) {
    const float* vi = (k & 1) ? v1 : v0;
    float* vo = (k & 1) ? v0 : v1;
    powmv<<<1024, 256, 0, stream>>>(Ab, vi, &slots[1 + k], vo, &slots[2 + k]);
  }
  rescale_f16<<<(NN * (size_t)NN) / 8 / 256, 256, 0, stream>>>(Ab, slots);
  scale_cast<<<(NN * (size_t)NN) / 4 / 256, 256, 0, stream>>>(H, slots, P0, 1);

  // --- quintic iterations ---
  f16* X = P0;
  f16* Y = P1;
  const float GA = 3.4445f, GB = -4.7750f, GC = 2.0315f;  // Muon growth
  const float PA = 1.875f, PB = -1.25f, PC = 0.375f;       // tangent polish

  for (int it = 0; it < NITER; ++it) {
    const bool polish = it >= NGROW;
    const bool last = (it == NITER - 1);
    const float qa = polish ? PA : GA, qb = polish ? PB : GB, qc = polish ? PC : GC;

    if (it > 0) {  // iteration 0 reuses the preamble's (rescaled) A
      transpose_h<<<gt, tb, 0, stream>>>((const unsigned short*)X, (unsigned short*)Y);
      gemm_nt<0, 1><<<NTRI, tb, 0, stream>>>(Y, Y, Ab, (f16*)nullptr, 0.0f, 1.0f);
    }
    f16* Bdst = last ? Y : Bb;  // final B must not alias d_out (race w/ C-write)
    gemm_nt<0, 1><<<NTRI, tb, 0, stream>>>(Ab, Ab, Bdst, Ab, qb, qc);
    if (!last) {
      gemm_nt<0, 0><<<gfull, tb, 0, stream>>>(X, Bdst, Y, X, qa, 1.0f);
      f16* t = X; X = Y; Y = t;
    } else {
      gemm_nt<1, 0><<<gfull, tb, 0, stream>>>(X, Bdst, out, X, qa, 1.0f);
    }
  }
}